// Round 1
// 1807.827 us; speedup vs baseline: 1.5844x; 1.5844x over previous
//
#include <hip/hip_runtime.h>
#include <hip/hip_bf16.h>

#define B_SZ 32
#define TS 128
#define TT 64
#define TD 63
#define E_DIM 256
#define H_DIM 512
#define G4 2048
#define V_TRG 30000
#define NWG_L 32   // workgroups per LSTM layer

typedef __attribute__((ext_vector_type(8))) short s8v;
typedef __attribute__((ext_vector_type(4))) float f32x4;
typedef unsigned short u16;
typedef unsigned long long u64;

static __device__ __forceinline__ float sigf(float x) {
  x = fminf(fmaxf(x, -30.f), 30.f);
  return 1.0f / (1.0f + __expf(-x));
}
static __device__ __forceinline__ float tanh_(float x) {
  x = fminf(fmaxf(x, -15.f), 15.f);
  float e = __expf(2.0f * x);
  return (e - 1.0f) / (e + 1.0f);
}
static __device__ __forceinline__ u16 f2bf(float x) {
  union { float f; unsigned u; } v; v.f = x;
  unsigned r = v.u + 0x7FFF + ((v.u >> 16) & 1);
  return (u16)(r >> 16);
}

// ---------------- weight fp32 -> bf16 conversion ----------------
struct Cvt { const float* s; u16* d; int n; };
struct Cvt9 { Cvt m[9]; };

__global__ void cvt_kernel(Cvt9 c) {
  const Cvt cv = c.m[blockIdx.y];
  int i = blockIdx.x * 256 + threadIdx.x;
  const int stride = gridDim.x * 256;
  for (; i < cv.n; i += stride) cv.d[i] = f2bf(cv.s[i]);
}

// ---------------- embedding gather (fp32 table -> bf16 x) ----------------
__global__ void embed_kernel(const int* __restrict__ tok, const float* __restrict__ emb,
                             u16* __restrict__ x, int rows, int tstride) {
  int i = blockIdx.x * 256 + threadIdx.x;
  if (i >= rows * E_DIM) return;
  int e = i & (E_DIM - 1);
  int r = i >> 8;
  int b = r & 31, t = r >> 5;
  int token = tok[b * tstride + t];
  x[i] = f2bf(emb[token * E_DIM + e]);
}

// ---------------- bf16 MFMA GEMM: C = A(MxK) @ W(NxK)^T + bias ----------------
// MODE 0: out[row*N + col] = v   (x-gate buffers, fp32)
// MODE 1: scatter logits: row = t*32+b -> out[b][t+1][col] (+fc_b)
template<int MODE>
__global__ __launch_bounds__(256) void gemm_bf16(
    const u16* __restrict__ A, const u16* __restrict__ Bw,
    const float* __restrict__ bias, float* __restrict__ out,
    int M, int N, int K) {
  __shared__ u16 As[128 * 40];   // row stride 40 u16 = 80B (16B pad)
  __shared__ u16 Bs[128 * 40];
  const int nb = blockIdx.x, mb = blockIdx.y;
  const int tid = threadIdx.x;
  const int w = tid >> 6, lane = tid & 63, quad = lane >> 4, cc = lane & 15;
  const int wm = w & 1, wn = w >> 1;
  f32x4 acc[4][4] = {};

  for (int k0 = 0; k0 < K; k0 += 32) {
    #pragma unroll
    for (int i = tid; i < 512; i += 256) {
      int m = i >> 2, kk = (i & 3) << 3;
      int gm = mb * 128 + m;
      s8v va = {};
      if (gm < M) va = *(const s8v*)(A + (size_t)gm * K + k0 + kk);
      *(s8v*)(&As[m * 40 + kk]) = va;
      int gn = nb * 128 + m;
      s8v vb = {};
      if (gn < N) vb = *(const s8v*)(Bw + (size_t)gn * K + k0 + kk);
      *(s8v*)(&Bs[m * 40 + kk]) = vb;
    }
    __syncthreads();
    s8v af[4], bf[4];
    #pragma unroll
    for (int mt = 0; mt < 4; ++mt)
      af[mt] = *(const s8v*)(&As[(wm * 64 + mt * 16 + cc) * 40 + quad * 8]);
    #pragma unroll
    for (int nt = 0; nt < 4; ++nt)
      bf[nt] = *(const s8v*)(&Bs[(wn * 64 + nt * 16 + cc) * 40 + quad * 8]);
    #pragma unroll
    for (int mt = 0; mt < 4; ++mt)
      #pragma unroll
      for (int nt = 0; nt < 4; ++nt)
        acc[mt][nt] = __builtin_amdgcn_mfma_f32_16x16x32_bf16(af[mt], bf[nt], acc[mt][nt], 0, 0, 0);
    __syncthreads();
  }

  #pragma unroll
  for (int mt = 0; mt < 4; ++mt)
    #pragma unroll
    for (int nt = 0; nt < 4; ++nt) {
      int col = nb * 128 + wn * 64 + nt * 16 + cc;
      if (col >= N) continue;
      float bv = bias[col];
      #pragma unroll
      for (int r = 0; r < 4; ++r) {
        int row = mb * 128 + wm * 64 + mt * 16 + quad * 4 + r;
        if (row >= M) continue;
        float v = acc[mt][nt][r] + bv;
        if (MODE == 0) {
          out[(size_t)row * N + col] = v;
        } else {
          int t = row >> 5, b = row & 31;
          out[(size_t)b * (TT * V_TRG) + (size_t)(t + 1) * V_TRG + col] = v;
        }
      }
    }
}

// ---------------- fused 2-layer pipelined LSTM scan ----------------
// grid 64 = 2 layers x 32 WGs (jn = 16 hidden cols each), block 128 (2 waves).
// Layer-1 runs one tick behind layer-0 (wavefront pipelining): serial chain is
// T+1 ticks instead of 2T. Layer-1 computes its x-gates (h0 @ Wih1^T) on the
// fly from an LDS-resident Wih1 slice (64KB Whh + 64KB Wih = 128KB LDS).
//
// Exchange: h written to PER-STEP UNIQUE addresses (H0x/H1x[t][32][512]) with
// relaxed agent-scope bypass stores (straight to IC, no L2 pollution/fences).
// Consumers use plain dwordx4 loads: addresses are never touched before the
// data is ready, so L1/L2 miss -> IC -> fresh.  Ordering: __syncthreads drains
// vmcnt(0) per wave before tid0's relaxed barrier-add; release is an all-thread
// relaxed spin + asm memory clobber (compiler fence, zero runtime cost).
// Per-layer decoupled counters: layer-0 never waits on layer-1; layer-1's
// h0-availability check (bar0) is almost always already satisfied, and its h0
// fragments are prefetched while it spins on its own-layer counter (bar1).
static __device__ __forceinline__ void spin_until(int* p, int target) {
  while (__hip_atomic_load(p, __ATOMIC_RELAXED, __HIP_MEMORY_SCOPE_AGENT) < target)
    __builtin_amdgcn_s_sleep(1);
}

__global__ __launch_bounds__(128, 1) void lstm2_scan(
    const float* __restrict__ Gx,      // [T][32][2048] layer-0 x-gates (incl bias)
    const u16* __restrict__ Whh0,      // [2048][512] bf16
    const u16* __restrict__ Wih1,      // [2048][512] bf16
    const u16* __restrict__ Whh1,      // [2048][512] bf16
    const float* __restrict__ b1,      // [2048] layer-1 bias
    const u16* __restrict__ h0i, const float* __restrict__ c0i,
    const u16* __restrict__ h1i, const float* __restrict__ c1i,
    u16* __restrict__ H0x,             // [T][32][512] layer-0 h exchange
    u16* __restrict__ H1x,             // [T][32][512] layer-1 h exchange/output
    u16* __restrict__ h0f, float* __restrict__ c0f,
    u16* __restrict__ h1f, float* __restrict__ c1f,
    int T, int* bar0, int* bar1) {
  __shared__ u16 BsH[64 * 512];        // Whh slice, k-chunk swizzled
  __shared__ u16 BsX[64 * 512];        // Wih1 slice (layer-1 WGs only)
  const bool L1 = (blockIdx.x >= NWG_L);
  const int jn = blockIdx.x & 31;
  const int tid = threadIdx.x;
  const int mt = tid >> 6, lane = tid & 63, quad = lane >> 4, cc = lane & 15;

  {
    const u16* Wh = L1 ? Whh1 : Whh0;
    for (int i = tid; i < 64 * 64; i += 128) {
      int col = i >> 6, kc = i & 63;
      int g = col >> 4, c = col & 15;
      int row = g * 512 + jn * 16 + c;
      s8v v = *(const s8v*)(Wh + (size_t)row * 512 + kc * 8);
      int kcs = (kc + col) & 63;
      *(s8v*)(&BsH[col * 512 + kcs * 8]) = v;
    }
    if (L1) {
      for (int i = tid; i < 64 * 64; i += 128) {
        int col = i >> 6, kc = i & 63;
        int g = col >> 4, c = col & 15;
        int row = g * 512 + jn * 16 + c;
        s8v v = *(const s8v*)(Wih1 + (size_t)row * 512 + kc * 8);
        int kcs = (kc + col) & 63;
        *(s8v*)(&BsX[col * 512 + kcs * 8]) = v;
      }
    }
  }
  __syncthreads();

  const int b0 = mt * 16 + quad * 4;
  const int j = jn * 16 + cc;
  const int arow = (mt * 16 + cc) * H_DIM + quad * 8;

  f32x4 creg;
  {
    const float* ci = L1 ? c1i : c0i;
    #pragma unroll
    for (int r = 0; r < 4; ++r) creg[r] = ci[(b0 + r) * H_DIM + j];
  }

  if (!L1) {
    // ---------------- layer 0 chain ----------------
    for (int s = 0; s < T; ++s) {
      // issue x-gate loads BEFORE the spin (overlap load latency with wait)
      float gx[4][4];
      #pragma unroll
      for (int g = 0; g < 4; ++g)
        #pragma unroll
        for (int r = 0; r < 4; ++r)
          gx[g][r] = Gx[(size_t)(s * B_SZ + b0 + r) * G4 + g * 512 + j];

      if (s > 0) {
        spin_until(bar0, NWG_L * s);
        asm volatile("" ::: "memory");
      }
      const u16* hsrc = (s == 0) ? h0i : (H0x + (size_t)(s - 1) * (B_SZ * H_DIM));
      f32x4 acc[4] = {};
      #pragma unroll
      for (int ks = 0; ks < 16; ++ks) {
        s8v a = *(const s8v*)(hsrc + arow + ks * 32);
        int kc = ks * 4 + quad;
        #pragma unroll
        for (int g = 0; g < 4; ++g) {
          int col = g * 16 + cc;
          int kcs = (kc + col) & 63;
          s8v bw = *(const s8v*)(&BsH[col * 512 + kcs * 8]);
          acc[g] = __builtin_amdgcn_mfma_f32_16x16x32_bf16(a, bw, acc[g], 0, 0, 0);
        }
      }
      u16* hw = H0x + (size_t)s * (B_SZ * H_DIM);
      #pragma unroll
      for (int r = 0; r < 4; ++r) {
        float gi = acc[0][r] + gx[0][r];
        float gf = acc[1][r] + gx[1][r];
        float gg = acc[2][r] + gx[2][r];
        float go = acc[3][r] + gx[3][r];
        float cn = sigf(gf) * creg[r] + sigf(gi) * tanh_(gg);
        float hn = sigf(go) * tanh_(cn);
        creg[r] = cn;
        u16 hb = f2bf(hn);
        __hip_atomic_store(&hw[(b0 + r) * H_DIM + j], hb,
                           __ATOMIC_RELAXED, __HIP_MEMORY_SCOPE_AGENT);
        if (s == T - 1) {
          h0f[(b0 + r) * H_DIM + j] = hb;
          c0f[(b0 + r) * H_DIM + j] = cn;
        }
      }
      __syncthreads();   // drains vmcnt(0) per wave -> stores IC-acked
      if (tid == 0)
        __hip_atomic_fetch_add(bar0, 1, __ATOMIC_RELAXED, __HIP_MEMORY_SCOPE_AGENT);
    }
  } else {
    // ---------------- layer 1 chain (one tick behind) ----------------
    float bv4[4];
    #pragma unroll
    for (int g = 0; g < 4; ++g) bv4[g] = b1[g * 512 + j];

    for (int s = 0; s < T; ++s) {
      // h0(s) availability (layer-0 is normally already ahead: single load)
      spin_until(bar0, NWG_L * (s + 1));
      asm volatile("" ::: "memory");
      const u16* h0src = H0x + (size_t)s * (B_SZ * H_DIM);
      s8v a0r[16];
      #pragma unroll
      for (int ks = 0; ks < 16; ++ks)
        a0r[ks] = *(const s8v*)(h0src + arow + ks * 32);

      if (s > 0) {
        spin_until(bar1, NWG_L * s);   // own-layer peers' h1(s-1)
        asm volatile("" ::: "memory");
      }
      const u16* h1src = (s == 0) ? h1i : (H1x + (size_t)(s - 1) * (B_SZ * H_DIM));
      f32x4 acc[4] = {};
      #pragma unroll
      for (int ks = 0; ks < 16; ++ks) {
        s8v a1 = *(const s8v*)(h1src + arow + ks * 32);
        int kc = ks * 4 + quad;
        #pragma unroll
        for (int g = 0; g < 4; ++g) {
          int col = g * 16 + cc;
          int kcs = (kc + col) & 63;
          s8v bh = *(const s8v*)(&BsH[col * 512 + kcs * 8]);
          s8v bx = *(const s8v*)(&BsX[col * 512 + kcs * 8]);
          acc[g] = __builtin_amdgcn_mfma_f32_16x16x32_bf16(a1, bh, acc[g], 0, 0, 0);
          acc[g] = __builtin_amdgcn_mfma_f32_16x16x32_bf16(a0r[ks], bx, acc[g], 0, 0, 0);
        }
      }
      u16* hw = H1x + (size_t)s * (B_SZ * H_DIM);
      #pragma unroll
      for (int r = 0; r < 4; ++r) {
        float gi = acc[0][r] + bv4[0];
        float gf = acc[1][r] + bv4[1];
        float gg = acc[2][r] + bv4[2];
        float go = acc[3][r] + bv4[3];
        float cn = sigf(gf) * creg[r] + sigf(gi) * tanh_(gg);
        float hn = sigf(go) * tanh_(cn);
        creg[r] = cn;
        u16 hb = f2bf(hn);
        __hip_atomic_store(&hw[(b0 + r) * H_DIM + j], hb,
                           __ATOMIC_RELAXED, __HIP_MEMORY_SCOPE_AGENT);
        if (s == T - 1) {
          h1f[(b0 + r) * H_DIM + j] = hb;
          c1f[(b0 + r) * H_DIM + j] = cn;
        }
      }
      __syncthreads();
      if (tid == 0 && s < T - 1)
        __hip_atomic_fetch_add(bar1, 1, __ATOMIC_RELAXED, __HIP_MEMORY_SCOPE_AGENT);
    }
  }
}

// ---------------- zero out[:, 0, :] ----------------
__global__ void zero_t0_kernel(float* __restrict__ out) {
  int i = blockIdx.x * 256 + threadIdx.x;
  if (i >= B_SZ * V_TRG) return;
  int b = i / V_TRG, v = i - b * V_TRG;
  out[(size_t)b * (TT * V_TRG) + v] = 0.f;
}

extern "C" void kernel_launch(void* const* d_in, const int* in_sizes, int n_in,
                              void* d_out, int out_size, void* d_ws, size_t ws_size,
                              hipStream_t stream) {
  const int*   src     = (const int*)d_in[0];
  const int*   trg     = (const int*)d_in[1];
  const float* enc_emb = (const float*)d_in[2];
  const float* dec_emb = (const float*)d_in[3];
  const float* eW0i = (const float*)d_in[4];
  const float* eW0h = (const float*)d_in[5];
  const float* eb0  = (const float*)d_in[6];
  const float* eW1i = (const float*)d_in[7];
  const float* eW1h = (const float*)d_in[8];
  const float* eb1  = (const float*)d_in[9];
  const float* dW0i = (const float*)d_in[10];
  const float* dW0h = (const float*)d_in[11];
  const float* db0  = (const float*)d_in[12];
  const float* dW1i = (const float*)d_in[13];
  const float* dW1h = (const float*)d_in[14];
  const float* db1  = (const float*)d_in[15];
  const float* fcW  = (const float*)d_in[16];
  const float* fcb  = (const float*)d_in[17];
  float* out = (float*)d_out;

  char* ws = (char*)d_ws;
  size_t off = 0;
  auto alloc = [&](size_t bytes) {
    char* p = ws + off;
    off = (off + bytes + 255) & ~(size_t)255;
    return p;
  };
  int*   bar    = (int*)alloc(1024);   // 4 counters, 128B apart
  u16*   hzero  = (u16*)alloc(B_SZ * H_DIM * 2);
  float* czero  = (float*)alloc(B_SZ * H_DIM * 4);
  u16* eW0i_b = (u16*)alloc((size_t)G4 * E_DIM * 2);
  u16* eW0h_b = (u16*)alloc((size_t)G4 * H_DIM * 2);
  u16* eW1i_b = (u16*)alloc((size_t)G4 * H_DIM * 2);
  u16* eW1h_b = (u16*)alloc((size_t)G4 * H_DIM * 2);
  u16* dW0i_b = (u16*)alloc((size_t)G4 * E_DIM * 2);
  u16* dW0h_b = (u16*)alloc((size_t)G4 * H_DIM * 2);
  u16* dW1i_b = (u16*)alloc((size_t)G4 * H_DIM * 2);
  u16* dW1h_b = (u16*)alloc((size_t)G4 * H_DIM * 2);
  u16* fcW_b  = (u16*)alloc((size_t)V_TRG * H_DIM * 2);
  u16* x_enc  = (u16*)alloc((size_t)TS * B_SZ * E_DIM * 2);
  u16* x_dec  = (u16*)alloc((size_t)TD * B_SZ * E_DIM * 2);
  float* Gx   = (float*)alloc((size_t)TS * B_SZ * G4 * 4);
  u16* H0e    = (u16*)alloc((size_t)TS * B_SZ * H_DIM * 2);  // enc L0 exchange
  u16* H1e    = (u16*)alloc((size_t)TS * B_SZ * H_DIM * 2);  // enc L1 exchange (finals only matter)
  u16* H0d    = (u16*)alloc((size_t)TD * B_SZ * H_DIM * 2);  // dec L0 exchange
  u16* H1d    = (u16*)alloc((size_t)TD * B_SZ * H_DIM * 2);  // dec L1 output -> FC head
  u16* hF0    = (u16*)alloc(B_SZ * H_DIM * 2);
  float* cF0  = (float*)alloc(B_SZ * H_DIM * 4);
  u16* hF1    = (u16*)alloc(B_SZ * H_DIM * 2);
  float* cF1  = (float*)alloc(B_SZ * H_DIM * 4);
  u16* hFd0   = (u16*)alloc(B_SZ * H_DIM * 2);
  float* cFd0 = (float*)alloc(B_SZ * H_DIM * 4);
  u16* hFd1   = (u16*)alloc(B_SZ * H_DIM * 2);
  float* cFd1 = (float*)alloc(B_SZ * H_DIM * 4);

  hipMemsetAsync(bar, 0, 1024, stream);
  hipMemsetAsync(hzero, 0, B_SZ * H_DIM * 2, stream);
  hipMemsetAsync(czero, 0, B_SZ * H_DIM * 4, stream);

  Cvt9 c9 = {{ {eW0i, eW0i_b, G4 * E_DIM}, {eW0h, eW0h_b, G4 * H_DIM},
               {eW1i, eW1i_b, G4 * H_DIM}, {eW1h, eW1h_b, G4 * H_DIM},
               {dW0i, dW0i_b, G4 * E_DIM}, {dW0h, dW0h_b, G4 * H_DIM},
               {dW1i, dW1i_b, G4 * H_DIM}, {dW1h, dW1h_b, G4 * H_DIM},
               {fcW,  fcW_b,  V_TRG * H_DIM} }};
  cvt_kernel<<<dim3(1024, 9), 256, 0, stream>>>(c9);

  embed_kernel<<<(TS * B_SZ * E_DIM + 255) / 256, 256, 0, stream>>>(src, enc_emb, x_enc, TS * B_SZ, TS);
  embed_kernel<<<(TD * B_SZ * E_DIM + 255) / 256, 256, 0, stream>>>(trg, dec_emb, x_dec, TD * B_SZ, TT);

  // encoder: x-gates GEMM for layer 0, then fused pipelined 2-layer scan
  gemm_bf16<0><<<dim3(16, 32), 256, 0, stream>>>(x_enc, eW0i_b, eb0, Gx, TS * B_SZ, G4, E_DIM);
  lstm2_scan<<<2 * NWG_L, 128, 0, stream>>>(
      Gx, eW0h_b, eW1i_b, eW1h_b, eb1,
      hzero, czero, hzero, czero,
      H0e, H1e, hF0, cF0, hF1, cF1, TS, bar + 0, bar + 32);

  // decoder: init = encoder final states
  gemm_bf16<0><<<dim3(16, 16), 256, 0, stream>>>(x_dec, dW0i_b, db0, Gx, TD * B_SZ, G4, E_DIM);
  lstm2_scan<<<2 * NWG_L, 128, 0, stream>>>(
      Gx, dW0h_b, dW1i_b, dW1h_b, db1,
      hF0, cF0, hF1, cF1,
      H0d, H1d, hFd0, cFd0, hFd1, cFd1, TD, bar + 64, bar + 96);

  // FC head: logits -> out[b][t+1][v]
  gemm_bf16<1><<<dim3((V_TRG + 127) / 128, (TD * B_SZ + 127) / 128), 256, 0, stream>>>(
      H1d, fcW_b, fcb, out, TD * B_SZ, V_TRG, H_DIM);
  zero_t0_kernel<<<(B_SZ * V_TRG + 255) / 256, 256, 0, stream>>>(out);
}